// Round 7
// baseline (475.945 us; speedup 1.0000x reference)
//
#include <hip/hip_runtime.h>
#include <hip/hip_bf16.h>

#define NTOK 8192
#define KP   64          // padded K (50 -> 64) for MFMA
#define EPSV 1e-8f

typedef __attribute__((ext_vector_type(4))) float f32x4;
typedef __attribute__((ext_vector_type(8))) short bf16x8;   // 8 bf16 in 4 VGPRs

// ---------------- Kernel 1: fused MLP -> coords(bf16, padded) + sq(f32) ----------------
__global__ __launch_bounds__(256) void k_mlp(
    const float* __restrict__ emb,
    const float* __restrict__ W1, const float* __restrict__ b1,
    const float* __restrict__ W2, const float* __restrict__ b2,
    const float* __restrict__ W3, const float* __restrict__ b3,
    __hip_bfloat16* __restrict__ coordsb, float* __restrict__ sqg)
{
    __shared__ float E[32 * 256];
    __shared__ float H1[32 * 128];
    __shared__ float H2[32 * 64];
    __shared__ float C3[32 * 50];

    const int tid  = threadIdx.x;
    const int brow = blockIdx.x * 32;

    // stage E tile [32][256] (coalesced float4)
    {
        const float4* src = (const float4*)(emb + (size_t)brow * 256);
        float4* dst = (float4*)E;
        for (int i = tid; i < 32 * 256 / 4; i += 256) dst[i] = src[i];
    }
    __syncthreads();

    // H1 = GELU(E @ W1 + b1): thread -> (col j, row-half rh), 16 rows each
    {
        const int j = tid & 127, rh = tid >> 7;
        float acc[16];
        const float bb = b1[j];
        #pragma unroll
        for (int r = 0; r < 16; ++r) acc[r] = bb;
        for (int k = 0; k < 256; k += 4) {
            const float w0 = W1[(k + 0) * 128 + j];
            const float w1 = W1[(k + 1) * 128 + j];
            const float w2 = W1[(k + 2) * 128 + j];
            const float w3 = W1[(k + 3) * 128 + j];
            #pragma unroll
            for (int r = 0; r < 16; ++r) {
                const float4 e = *(const float4*)&E[(rh * 16 + r) * 256 + k];
                acc[r] = fmaf(e.x, w0, acc[r]);
                acc[r] = fmaf(e.y, w1, acc[r]);
                acc[r] = fmaf(e.z, w2, acc[r]);
                acc[r] = fmaf(e.w, w3, acc[r]);
            }
        }
        #pragma unroll
        for (int r = 0; r < 16; ++r) {
            const float h = acc[r];
            H1[(rh * 16 + r) * 128 + j] = 0.5f * h * (1.0f + erff(h * 0.70710678118654752f));
        }
    }
    __syncthreads();

    // H2 = GELU(H1 @ W2 + b2): thread -> (col j, row-quarter rg), 8 rows each
    {
        const int j = tid & 63, rg = tid >> 6;
        float acc[8];
        const float bb = b2[j];
        #pragma unroll
        for (int r = 0; r < 8; ++r) acc[r] = bb;
        for (int k = 0; k < 128; k += 4) {
            const float w0 = W2[(k + 0) * 64 + j];
            const float w1 = W2[(k + 1) * 64 + j];
            const float w2v = W2[(k + 2) * 64 + j];
            const float w3v = W2[(k + 3) * 64 + j];
            #pragma unroll
            for (int r = 0; r < 8; ++r) {
                const float4 h = *(const float4*)&H1[(rg * 8 + r) * 128 + k];
                acc[r] = fmaf(h.x, w0, acc[r]);
                acc[r] = fmaf(h.y, w1, acc[r]);
                acc[r] = fmaf(h.z, w2v, acc[r]);
                acc[r] = fmaf(h.w, w3v, acc[r]);
            }
        }
        #pragma unroll
        for (int r = 0; r < 8; ++r) {
            const float h = acc[r];
            H2[(rg * 8 + r) * 64 + j] = 0.5f * h * (1.0f + erff(h * 0.70710678118654752f));
        }
    }
    __syncthreads();

    // coords = H2 @ W3 + b3  (32 x 50)
    for (int o = tid; o < 32 * 50; o += 256) {
        const int r = o / 50;
        const int c = o - r * 50;
        float acc = b3[c];
        for (int k = 0; k < 64; k += 4) {
            const float4 h = *(const float4*)&H2[r * 64 + k];
            acc = fmaf(h.x, W3[(k + 0) * 50 + c], acc);
            acc = fmaf(h.y, W3[(k + 1) * 50 + c], acc);
            acc = fmaf(h.z, W3[(k + 2) * 50 + c], acc);
            acc = fmaf(h.w, W3[(k + 3) * 50 + c], acc);
        }
        C3[o] = acc;
    }
    __syncthreads();

    // sq (exact fp32) and bf16 coords (zero-padded to KP)
    if (tid < 32) {
        float s = 0.0f;
        for (int c = 0; c < 50; ++c) { const float v = C3[tid * 50 + c]; s = fmaf(v, v, s); }
        sqg[brow + tid] = s;
    }
    for (int i = tid; i < 32 * KP; i += 256) {
        const int r = i >> 6, c = i & 63;
        const float v = (c < 50) ? C3[r * 50 + c] : 0.0f;
        coordsb[(size_t)(brow + r) * KP + c] = __float2bfloat16(v);
    }
}

// ---------------- Kernel 2: softmax -> tiled w_full; zero rowsum ----------------
__global__ __launch_bounds__(256) void k_wfull(
    const float* __restrict__ dw, float* __restrict__ wfull, float* __restrict__ rowsum)
{
    __shared__ float w[50];
    const int tid = threadIdx.x;
    if (tid < 50) w[tid] = dw[tid];
    __syncthreads();
    float m = -1e30f;
    for (int i = 0; i < 50; ++i) m = fmaxf(m, w[i]);
    float s = 0.0f;
    for (int i = 0; i < 50; ++i) s += __expf(w[i] - m);
    const float inv = 1.0f / s;
    const int i = blockIdx.x * 256 + tid;
    const int c = i % 50;
    wfull[i]  = __expf(w[c] - m) * inv;
    rowsum[i] = 0.0f;
}

// ---------------- Kernel 3: row sums of weighted gaussian kernel ----------------
__global__ __launch_bounds__(256) void k_rowsum(
    const unsigned short* __restrict__ Xb, const float* __restrict__ sqg,
    const float* __restrict__ wfull, const float* __restrict__ sigp,
    float* __restrict__ rowsum)
{
    const int tid  = threadIdx.x;
    const int lane = tid & 63;
    const int wv   = tid >> 6;
    const int r0   = blockIdx.x * 64 + wv * 16;
    const int m0   = blockIdx.y * 1024;
    const int lr   = lane & 15;   // A-row / B-col / C-col
    const int lk   = lane >> 4;   // k-slice group

    const float sg    = fminf(fmaxf(sigp[0], 0.1f), 10.0f);
    const float scale = -1.4426950408889634f / (2.0f * sg * sg);   // exp(-d2/2s^2) = 2^(d2*scale)

    const bf16x8 a0 = *(const bf16x8*)(Xb + (size_t)(r0 + lr) * KP + 0 * 32 + lk * 8);
    const bf16x8 a1 = *(const bf16x8*)(Xb + (size_t)(r0 + lr) * KP + 1 * 32 + lk * 8);
    float sqn[4];
    #pragma unroll
    for (int j = 0; j < 4; ++j) sqn[j] = sqg[r0 + lk * 4 + j];

    float rs[4] = {0.f, 0.f, 0.f, 0.f};
    for (int mt = m0; mt < m0 + 1024; mt += 16) {
        const bf16x8 bA = *(const bf16x8*)(Xb + (size_t)(mt + lr) * KP + 0 * 32 + lk * 8);
        const bf16x8 bB = *(const bf16x8*)(Xb + (size_t)(mt + lr) * KP + 1 * 32 + lk * 8);
        f32x4 acc = {0.f, 0.f, 0.f, 0.f};
        acc = __builtin_amdgcn_mfma_f32_16x16x32_bf16(a0, bA, acc, 0, 0, 0);
        acc = __builtin_amdgcn_mfma_f32_16x16x32_bf16(a1, bB, acc, 0, 0, 0);
        const float sqm = sqg[mt + lr];
        const float wm  = wfull[mt + lr];
        #pragma unroll
        for (int j = 0; j < 4; ++j) {
            const float d2 = fmaxf(sqn[j] + sqm - 2.0f * acc[j], 0.0f);
            rs[j] += exp2f(d2 * scale) * wm;
        }
    }
    #pragma unroll
    for (int j = 0; j < 4; ++j) {
        float v = rs[j];
        v += __shfl_xor(v, 1);
        v += __shfl_xor(v, 2);
        v += __shfl_xor(v, 4);
        v += __shfl_xor(v, 8);
        if (lr == 0) atomicAdd(&rowsum[r0 + lk * 4 + j], v);
    }
}

// ---------------- Kernel 4: recompute (A=m-tile, B=n-tile), normalize, float4 store ----------------
// C layout: col(lane&15) = n-local, row(lk*4+j) = m-local  =>  each lane owns 4
// consecutive m-columns of ONE output row -> one aligned float4 store per tile.
__global__ __launch_bounds__(256) void k_out(
    const unsigned short* __restrict__ Xb, const float* __restrict__ sqg,
    const float* __restrict__ wfull, const float* __restrict__ sigp,
    const float* __restrict__ rowsum, float* __restrict__ out)
{
    const int tid  = threadIdx.x;
    const int lane = tid & 63;
    const int wv   = tid >> 6;
    const int n0   = blockIdx.x * 64 + wv * 16;
    const int m0   = blockIdx.y * 1024;
    const int lr   = lane & 15;   // n-local (B col / C col)
    const int lk   = lane >> 4;   // k-slice group / C row group

    const float sg    = fminf(fmaxf(sigp[0], 0.1f), 10.0f);
    const float scale = -1.4426950408889634f / (2.0f * sg * sg);

    // B operand: n-tile rows (fixed per wave)
    const bf16x8 b0 = *(const bf16x8*)(Xb + (size_t)(n0 + lr) * KP + 0 * 32 + lk * 8);
    const bf16x8 b1 = *(const bf16x8*)(Xb + (size_t)(n0 + lr) * KP + 1 * 32 + lk * 8);
    const float sqn_l = sqg[n0 + lr];
    const float inv_l = 1.0f / (rowsum[n0 + lr] + EPSV);

    for (int mt = m0; mt < m0 + 1024; mt += 16) {
        // A operand: m-tile rows
        const bf16x8 aA = *(const bf16x8*)(Xb + (size_t)(mt + lr) * KP + 0 * 32 + lk * 8);
        const bf16x8 aB = *(const bf16x8*)(Xb + (size_t)(mt + lr) * KP + 1 * 32 + lk * 8);
        f32x4 acc = {0.f, 0.f, 0.f, 0.f};
        acc = __builtin_amdgcn_mfma_f32_16x16x32_bf16(aA, b0, acc, 0, 0, 0);
        acc = __builtin_amdgcn_mfma_f32_16x16x32_bf16(aB, b1, acc, 0, 0, 0);

        const float4 sqm4 = *(const float4*)&sqg[mt + lk * 4];
        const float4 wm4  = *(const float4*)&wfull[mt + lk * 4];

        float4 o;
        {
            const float d2x = fmaxf(sqn_l + sqm4.x - 2.0f * acc[0], 0.0f);
            const float d2y = fmaxf(sqn_l + sqm4.y - 2.0f * acc[1], 0.0f);
            const float d2z = fmaxf(sqn_l + sqm4.z - 2.0f * acc[2], 0.0f);
            const float d2w = fmaxf(sqn_l + sqm4.w - 2.0f * acc[3], 0.0f);
            o.x = exp2f(d2x * scale) * wm4.x * inv_l;
            o.y = exp2f(d2y * scale) * wm4.y * inv_l;
            o.z = exp2f(d2z * scale) * wm4.z * inv_l;
            o.w = exp2f(d2w * scale) * wm4.w * inv_l;
        }
        *(float4*)&out[(size_t)(n0 + lr) * NTOK + mt + lk * 4] = o;
    }
}

extern "C" void kernel_launch(void* const* d_in, const int* in_sizes, int n_in,
                              void* d_out, int out_size, void* d_ws, size_t ws_size,
                              hipStream_t stream)
{
    const float* emb = (const float*)d_in[0];
    const float* W1  = (const float*)d_in[1];
    const float* b1  = (const float*)d_in[2];
    const float* W2  = (const float*)d_in[3];
    const float* b2  = (const float*)d_in[4];
    const float* W3  = (const float*)d_in[5];
    const float* b3  = (const float*)d_in[6];
    const float* dw  = (const float*)d_in[7];
    const float* sig = (const float*)d_in[8];
    float* out = (float*)d_out;

    char* ws = (char*)d_ws;
    __hip_bfloat16* coordsb = (__hip_bfloat16*)ws;                 // 8192*64*2 = 1 MiB
    float* sqg    = (float*)(ws + 1048576);                        // 32 KiB
    float* wfull  = (float*)(ws + 1048576 + 32768);                // 32 KiB
    float* rowsum = (float*)(ws + 1048576 + 65536);                // 32 KiB

    hipLaunchKernelGGL(k_mlp, dim3(NTOK / 32), dim3(256), 0, stream,
                       emb, W1, b1, W2, b2, W3, b3, coordsb, sqg);
    hipLaunchKernelGGL(k_wfull, dim3(NTOK / 256), dim3(256), 0, stream, dw, wfull, rowsum);
    hipLaunchKernelGGL(k_rowsum, dim3(NTOK / 64, 8), dim3(256), 0, stream,
                       (const unsigned short*)coordsb, sqg, wfull, sig, rowsum);
    hipLaunchKernelGGL(k_out, dim3(NTOK / 64, 8), dim3(256), 0, stream,
                       (const unsigned short*)coordsb, sqg, wfull, sig, rowsum, out);
}